// Round 10
// baseline (271.758 us; speedup 1.0000x reference)
//
#include <hip/hip_runtime.h>

#define NPTS 8192
#define DIM 64
#define BATCH 2
#define KOUT 17
#define QCAP 40     // queue capacity per (row, seg)
#define THRANK 21   // theta = 22nd smallest of the 64-subset

typedef float f32x4 __attribute__((ext_vector_type(4)));
typedef short short8 __attribute__((ext_vector_type(8)));
typedef unsigned int uint4v __attribute__((ext_vector_type(4)));

#define MFMA16(A, B, C) __builtin_amdgcn_mfma_f32_16x16x32_bf16(A, B, C, 0, 0, 0)

// ---------- prep: permuted hi/lo bf16 (phl), contiguous f32 (pct), 0.5*|x|^2 ----------
__global__ __launch_bounds__(256)
void prep_kernel(const float* __restrict__ pc, ushort* __restrict__ phl,
                 float* __restrict__ pct, float* __restrict__ sq) {
  __shared__ double psum[256];
  int t = threadIdx.x;
  int u = t >> 5;           // 0..7  (dims u*8 .. u*8+7)
  int p = t & 31;           // 0..31 (point within block)
  int i = blockIdx.x * 32 + p;   // 0..16383
  int b = i >> 13, n = i & (NPTS - 1);
  const float* g = pc + (size_t)b * DIM * NPTS + n;

  float x[8];
  short8 hv, lv;
  double s = 0.0;
  #pragma unroll
  for (int e = 0; e < 8; ++e) {
    x[e] = g[(size_t)(u * 8 + e) * NPTS];
    s += (double)x[e] * (double)x[e];
    unsigned uu = __float_as_uint(x[e]);
    unsigned r = uu + (0x7fffu + ((uu >> 16) & 1));
    unsigned hi = r >> 16;                       // bf16 RNE
    float xl = x[e] - __uint_as_float(hi << 16);
    unsigned ul = __float_as_uint(xl);
    unsigned rl = ul + (0x7fffu + ((ul >> 16) & 1));
    hv[e] = (short)(hi & 0xffffu);
    lv[e] = (short)((rl >> 16) & 0xffffu);
  }
  int slot = u ^ (n & 7);
  ushort* ph = phl + (size_t)i * 128;
  *(short8*)(ph + slot * 8) = hv;
  *(short8*)(ph + 64 + slot * 8) = lv;
  f32x4 v0 = {x[0], x[1], x[2], x[3]}, v1 = {x[4], x[5], x[6], x[7]};
  *(f32x4*)(pct + (size_t)i * 64 + u * 8) = v0;
  *(f32x4*)(pct + (size_t)i * 64 + u * 8 + 4) = v1;

  psum[u * 32 + p] = s;
  __syncthreads();
  if (t < 32) {
    double acc = 0.0;
    #pragma unroll
    for (int uu = 0; uu < 8; ++uu) acc += psum[uu * 32 + t];
    sq[blockIdx.x * 32 + t] = (float)(0.5 * acc);   // HALF |x|^2
  }
}

// ---------- two-pass MFMA distance + theta-filter, direct-global B with reg prefetch ----------
// 1024 blocks x 256 threads. XCD-partitioned mapping: orig&7 selects (b,seg) pair so each
// XCD's L2 holds one 2 MB B-stream. Block = 32 rows x 4096 cols (32 tiles of 128).
__global__ __launch_bounds__(256, 3)
void knn_kernel(const ushort* __restrict__ phl, const float* __restrict__ sq,
                ushort* __restrict__ cand) {
  __shared__ float KT[32 * 128];   // 16 KB
  __shared__ float KT2[32 * 64];   // 8 KB
  __shared__ float TH[32];
  __shared__ int CNT[32];
  __shared__ ushort QU[32][QCAP];

  int t = threadIdx.x;
  int lane = t & 63;
  int w = t >> 6;
  int orig = blockIdx.x;
  int x8 = orig & 7;
  int b = x8 >> 2;                 // (x8>>1)>>1
  int seg = (x8 >> 1) & 1;
  int row0 = ((orig >> 3) * 2 + (x8 & 1)) * 32;
  const ushort* pb = phl + (size_t)b * NPTS * 128;
  const float* sqb = sq + b * NPTS;

  int c15 = lane & 15, l4 = lane >> 4;
  int ccol = w * 32;
  int sw8 = c15 & 7;
  int so0 = (l4 ^ sw8) * 8;          // kk=0 slot offset (ushorts)
  int so1 = ((4 + l4) ^ sw8) * 8;    // kk=1
  int base = seg * 4096;

  const ushort* pb0 = pb + (size_t)(ccol + c15) * 128;
  const ushort* pb1 = pb + (size_t)(ccol + 16 + c15) * 128;

  // A fragments [hl][kk][rg], rows row0 + rg*16 + c15, sign-flipped (exact)
  short8 a[2][2][2];
  #pragma unroll
  for (int rg = 0; rg < 2; ++rg) {
    int n = row0 + rg * 16 + c15;
    const ushort* pr = pb + (size_t)n * 128;
    #pragma unroll
    for (int hl = 0; hl < 2; ++hl)
      #pragma unroll
      for (int kk = 0; kk < 2; ++kk) {
        int slot = (kk * 4 + l4) ^ (n & 7);
        short8 v = *(const short8*)(pr + hl * 64 + slot * 8);
        uint4v uv = *(uint4v*)&v;
        uv ^= 0x80008000u;
        a[hl][kk][rg] = *(short8*)&uv;
      }
  }

#define LOADB(BUF, N0) { \
    size_t off_ = (size_t)(N0) * 128; \
    const ushort* q0_ = pb0 + off_; \
    const ushort* q1_ = pb1 + off_; \
    BUF[0] = *(const short8*)(q0_ + so0); \
    BUF[1] = *(const short8*)(q0_ + 64 + so0); \
    BUF[2] = *(const short8*)(q0_ + so1); \
    BUF[3] = *(const short8*)(q0_ + 64 + so1); \
    BUF[4] = *(const short8*)(q1_ + so0); \
    BUF[5] = *(const short8*)(q1_ + 64 + so0); \
    BUF[6] = *(const short8*)(q1_ + so1); \
    BUF[7] = *(const short8*)(q1_ + 64 + so1); }

#define KEYS4(BUF, SV0, SV1, CA, CB, CC, CD) \
    f32x4 CA = {SV0, SV0, SV0, SV0}, CB = CA; \
    CA = MFMA16(a[0][0][0], BUF[0], CA); CB = MFMA16(a[0][0][1], BUF[0], CB); \
    CA = MFMA16(a[0][0][0], BUF[1], CA); CB = MFMA16(a[0][0][1], BUF[1], CB); \
    CA = MFMA16(a[1][0][0], BUF[0], CA); CB = MFMA16(a[1][0][1], BUF[0], CB); \
    CA = MFMA16(a[0][1][0], BUF[2], CA); CB = MFMA16(a[0][1][1], BUF[2], CB); \
    CA = MFMA16(a[0][1][0], BUF[3], CA); CB = MFMA16(a[0][1][1], BUF[3], CB); \
    CA = MFMA16(a[1][1][0], BUF[2], CA); CB = MFMA16(a[1][1][1], BUF[2], CB); \
    f32x4 CC = {SV1, SV1, SV1, SV1}, CD = CC; \
    CC = MFMA16(a[0][0][0], BUF[4], CC); CD = MFMA16(a[0][0][1], BUF[4], CD); \
    CC = MFMA16(a[0][0][0], BUF[5], CC); CD = MFMA16(a[0][0][1], BUF[5], CD); \
    CC = MFMA16(a[1][0][0], BUF[4], CC); CD = MFMA16(a[1][0][1], BUF[4], CD); \
    CC = MFMA16(a[0][1][0], BUF[6], CC); CD = MFMA16(a[0][1][1], BUF[6], CD); \
    CC = MFMA16(a[0][1][0], BUF[7], CC); CD = MFMA16(a[0][1][1], BUF[7], CD); \
    CC = MFMA16(a[1][1][0], BUF[6], CC); CD = MFMA16(a[1][1][1], BUF[6], CD);

  // ================= PASS A: per-lane top-2 per owned row (8 rows/lane) =================
  float k1[2][4], k2[2][4];
  #pragma unroll
  for (int rg = 0; rg < 2; ++rg)
    #pragma unroll
    for (int r = 0; r < 4; ++r) { k1[rg][r] = __builtin_inff(); k2[rg][r] = __builtin_inff(); }

#define SELA(CA, CB, CC, CD) { \
    _Pragma("unroll") \
    for (int r = 0; r < 4; ++r) { \
      k2[0][r] = __builtin_amdgcn_fmed3f(CA[r], k1[0][r], k2[0][r]); \
      k1[0][r] = fminf(CA[r], k1[0][r]); \
      k2[1][r] = __builtin_amdgcn_fmed3f(CB[r], k1[1][r], k2[1][r]); \
      k1[1][r] = fminf(CB[r], k1[1][r]); \
      k2[0][r] = __builtin_amdgcn_fmed3f(CC[r], k1[0][r], k2[0][r]); \
      k1[0][r] = fminf(CC[r], k1[0][r]); \
      k2[1][r] = __builtin_amdgcn_fmed3f(CD[r], k1[1][r], k2[1][r]); \
      k1[1][r] = fminf(CD[r], k1[1][r]); \
    } }

  {
    short8 bufA[8], bufB[8];
    float sqA0, sqA1, sqB0, sqB1;
    LOADB(bufA, base);
    sqA0 = sqb[base + ccol + c15];
    sqA1 = sqb[base + ccol + 16 + c15];
    for (int tile = 0; tile < 32; tile += 2) {
      int n0e = base + tile * 128;
      int n0o = n0e + 128;
      int n0n = (tile + 2 < 32) ? n0e + 256 : base;
      LOADB(bufB, n0o);
      sqB0 = sqb[n0o + ccol + c15];
      sqB1 = sqb[n0o + ccol + 16 + c15];
      { KEYS4(bufA, sqA0, sqA1, cA, cB, cC, cD); SELA(cA, cB, cC, cD); }
      LOADB(bufA, n0n);
      sqA0 = sqb[n0n + ccol + c15];
      sqA1 = sqb[n0n + ccol + 16 + c15];
      { KEYS4(bufB, sqB0, sqB1, cA, cB, cC, cD); SELA(cA, cB, cC, cD); }
    }
  }

  // ================= subset: KT[32][128], then pair-merge to KT2[32][64] =================
  __syncthreads();
  #pragma unroll
  for (int rg = 0; rg < 2; ++rg)
    #pragma unroll
    for (int r = 0; r < 4; ++r) {
      int row = rg * 16 + l4 * 4 + r;
      KT[row * 128 + (w * 16 + c15) * 2] = k1[rg][r];
      KT[row * 128 + (w * 16 + c15) * 2 + 1] = k2[rg][r];
    }
  __syncthreads();
  #pragma unroll
  for (int it = 0; it < 4; ++it) {
    int idx = t + it * 256;               // 0..1023
    int row = idx >> 5, j = idx & 31;
    float a1 = KT[row * 128 + j * 2], a2 = KT[row * 128 + j * 2 + 1];
    float b1 = KT[row * 128 + 64 + j * 2], b2 = KT[row * 128 + 64 + j * 2 + 1];
    KT2[row * 64 + j * 2] = fminf(a1, b1);
    KT2[row * 64 + j * 2 + 1] = fminf(fmaxf(a1, b1), fminf(a2, b2));
  }
  __syncthreads();

  // ================= theta per row = 22nd smallest of 64-subset =================
  {
    int row = t >> 3;
    int j0 = (t & 7) * 8;
    const f32x4* vr4 = (const f32x4*)(KT2 + row * 64);
    float vj[8];
    *(f32x4*)vj = vr4[(t & 7) * 2];
    *(f32x4*)(vj + 4) = vr4[(t & 7) * 2 + 1];
    int rank[8];
    #pragma unroll
    for (int jj = 0; jj < 8; ++jj) rank[jj] = 0;
    for (int m4 = 0; m4 < 16; ++m4) {
      f32x4 vm = vr4[m4];
      #pragma unroll
      for (int e = 0; e < 4; ++e) {
        int m = m4 * 4 + e;
        float ve = vm[e];
        #pragma unroll
        for (int jj = 0; jj < 8; ++jj)
          rank[jj] += (ve < vj[jj] || (ve == vj[jj] && m < j0 + jj)) ? 1 : 0;
      }
    }
    #pragma unroll
    for (int jj = 0; jj < 8; ++jj)
      if (rank[jj] == THRANK) TH[row] = vj[jj];
    if (t < 32) CNT[t] = 0;
  }
  __syncthreads();
  float th[2][4];
  #pragma unroll
  for (int rg = 0; rg < 2; ++rg)
    #pragma unroll
    for (int r = 0; r < 4; ++r) th[rg][r] = TH[rg * 16 + l4 * 4 + r];

  // ================= PASS B: recompute + collect key<=theta =================
#define SELB(CA, CB, CC, CD, N0) { \
    int p0_ = (N0) + ccol + c15; \
    int p1_ = (N0) + ccol + 16 + c15; \
    _Pragma("unroll") \
    for (int r = 0; r < 4; ++r) { \
      if (CA[r] <= th[0][r]) { int row_ = l4 * 4 + r; \
        int pos_ = atomicAdd(&CNT[row_], 1); \
        if (pos_ < QCAP) QU[row_][pos_] = (ushort)p0_; } \
      if (CB[r] <= th[1][r]) { int row_ = 16 + l4 * 4 + r; \
        int pos_ = atomicAdd(&CNT[row_], 1); \
        if (pos_ < QCAP) QU[row_][pos_] = (ushort)p0_; } \
      if (CC[r] <= th[0][r]) { int row_ = l4 * 4 + r; \
        int pos_ = atomicAdd(&CNT[row_], 1); \
        if (pos_ < QCAP) QU[row_][pos_] = (ushort)p1_; } \
      if (CD[r] <= th[1][r]) { int row_ = 16 + l4 * 4 + r; \
        int pos_ = atomicAdd(&CNT[row_], 1); \
        if (pos_ < QCAP) QU[row_][pos_] = (ushort)p1_; } \
    } }

  {
    short8 bufA[8], bufB[8];
    float sqA0, sqA1, sqB0, sqB1;
    LOADB(bufA, base);
    sqA0 = sqb[base + ccol + c15];
    sqA1 = sqb[base + ccol + 16 + c15];
    for (int tile = 0; tile < 32; tile += 2) {
      int n0e = base + tile * 128;
      int n0o = n0e + 128;
      int n0n = (tile + 2 < 32) ? n0e + 256 : base;
      LOADB(bufB, n0o);
      sqB0 = sqb[n0o + ccol + c15];
      sqB1 = sqb[n0o + ccol + 16 + c15];
      { KEYS4(bufA, sqA0, sqA1, cA, cB, cC, cD); SELB(cA, cB, cC, cD, n0e); }
      LOADB(bufA, n0n);
      sqA0 = sqb[n0n + ccol + c15];
      sqA1 = sqb[n0n + ccol + 16 + c15];
      { KEYS4(bufB, sqB0, sqB1, cA, cB, cC, cD); SELB(cA, cB, cC, cD, n0o); }
    }
  }

  // ================= pad + dump queues =================
  __syncthreads();
  for (int i = t; i < 32 * QCAP; i += 256) {
    int row = i / QCAP, s2 = i % QCAP;
    int c2 = CNT[row]; if (c2 > QCAP) c2 = QCAP;
    ushort v = (s2 < c2) ? QU[row][s2] : (ushort)0xFFFFu;
    cand[((size_t)(b * NPTS + row0 + row) * 2 + seg) * QCAP + s2] = v;
  }
}

// ---------- exact f64 re-rank of up to 80 candidates, wave per point ----------
__global__ void refine_kernel(const float* __restrict__ pct, const ushort* __restrict__ cand,
                              int* __restrict__ knn, float* __restrict__ idxf) {
  int gw = (blockIdx.x * 256 + threadIdx.x) >> 6;  // 0..16383
  int lane = threadIdx.x & 63;
  int b = gw >> 13, n = gw & (NPTS - 1);
  const float* pcb = pct + (size_t)b * NPTS * 64;
  const ushort* cb = cand + (size_t)gw * (2 * QCAP);
  const float* qp = pcb + (size_t)n * 64;

  unsigned ciA = cb[lane];
  unsigned ciB = (lane < 2 * QCAP - 64) ? (unsigned)cb[64 + lane] : 0xFFFFu;
  double dA = __builtin_inf(), dB = __builtin_inf();
  if (ciA != 0xFFFFu) {
    const float* cp = pcb + (size_t)ciA * 64;
    double s = 0.0;
    #pragma unroll
    for (int u = 0; u < 16; ++u) {
      f32x4 cv = *(const f32x4*)(cp + u * 4);
      f32x4 qv = *(const f32x4*)(qp + u * 4);
      #pragma unroll
      for (int e = 0; e < 4; ++e) {
        double diff = (double)cv[e] - (double)qv[e];
        s = fma(diff, diff, s);
      }
    }
    dA = s;
  }
  if (ciB != 0xFFFFu) {
    const float* cp = pcb + (size_t)ciB * 64;
    double s = 0.0;
    #pragma unroll
    for (int u = 0; u < 16; ++u) {
      f32x4 cv = *(const f32x4*)(cp + u * 4);
      f32x4 qv = *(const f32x4*)(qp + u * 4);
      #pragma unroll
      for (int e = 0; e < 4; ++e) {
        double diff = (double)cv[e] - (double)qv[e];
        s = fma(diff, diff, s);
      }
    }
    dB = s;
  }

  int rA = 0, rB = 0;
  for (int j = 0; j < 64; ++j) {
    double dk = __shfl(dA, j);
    unsigned ik = (unsigned)__shfl((int)ciA, j);
    rA += ((dk < dA) || (dk == dA && ik < ciA)) ? 1 : 0;
    rB += ((dk < dB) || (dk == dB && ik < ciB)) ? 1 : 0;
  }
  for (int j = 0; j < 2 * QCAP - 64; ++j) {
    double dk = __shfl(dB, j);
    unsigned ik = (unsigned)__shfl((int)ciB, j);
    rA += ((dk < dA) || (dk == dA && ik < ciA)) ? 1 : 0;
    rB += ((dk < dB) || (dk == dB && ik < ciB)) ? 1 : 0;
  }
  if (ciA != 0xFFFFu && rA < KOUT) {
    size_t o = ((size_t)b * KOUT + rA) * NPTS + n;
    knn[o] = (int)ciA;
    idxf[o] = (float)ciA;
  }
  if (lane < 2 * QCAP - 64 && ciB != 0xFFFFu && rB < KOUT) {
    size_t o = ((size_t)b * KOUT + rB) * NPTS + n;
    knn[o] = (int)ciB;
    idxf[o] = (float)ciB;
  }
}

// ---------- edge features: out [B][128][17][N]; block = (n-chunk, b*64+c), k-loop inside ----------
__global__ __launch_bounds__(256)
void edge_kernel(const float* __restrict__ pc, const int* __restrict__ knn,
                 float* __restrict__ out) {
  int n = blockIdx.x * 256 + threadIdx.x;
  int z = blockIdx.y;
  int b = z >> 6, c = z & 63;
  const float* row = pc + ((size_t)b * DIM + c) * NPTS;
  float central = row[n];
  size_t base = (((size_t)b * 2 * DIM + c) * KOUT) * NPTS + n;
  const int* kb = knn + (size_t)b * KOUT * NPTS + n;
  #pragma unroll
  for (int k = 0; k < KOUT; ++k) {
    int nb = kb[(size_t)k * NPTS];
    float nbrv = row[nb];
    out[base + (size_t)k * NPTS] = central;
    out[base + (size_t)(DIM * KOUT + k) * NPTS] = nbrv - central;
  }
}

extern "C" void kernel_launch(void* const* d_in, const int* in_sizes, int n_in,
                              void* d_out, int out_size, void* d_ws, size_t ws_size,
                              hipStream_t stream) {
  const float* pc = (const float*)d_in[0];
  float* out = (float*)d_out;
  char* ws = (char*)d_ws;
  ushort* phl = (ushort*)ws;                                     // 4 MB
  float* pct  = (float*)(ws + (size_t)4 * 1024 * 1024);          // 4 MB
  float* sq   = (float*)(ws + (size_t)8 * 1024 * 1024);          // 64 KB
  ushort* cand = (ushort*)(ws + (size_t)8 * 1024 * 1024 + 65536);
  int* knn    = (int*)(ws + (size_t)8 * 1024 * 1024 + 65536 + (size_t)16384 * 2 * QCAP * 2);

  float* idxf = out + (size_t)BATCH * 2 * DIM * KOUT * NPTS;

  prep_kernel<<<512, 256, 0, stream>>>(pc, phl, pct, sq);
  knn_kernel<<<1024, 256, 0, stream>>>(phl, sq, cand);
  refine_kernel<<<4096, 256, 0, stream>>>(pct, cand, knn, idxf);
  edge_kernel<<<dim3(NPTS / 256, BATCH * DIM), 256, 0, stream>>>(pc, knn, out);
}

// Round 11
// 232.186 us; speedup vs baseline: 1.1704x; 1.1704x over previous
//
#include <hip/hip_runtime.h>

#define NPTS 8192
#define DIM 64
#define BATCH 2
#define KOUT 17
#define QCAP 40     // queue capacity per (row, seg)
#define THRANK 21   // theta = 22nd smallest of the 64-subset

typedef float f32x4 __attribute__((ext_vector_type(4)));
typedef short short8 __attribute__((ext_vector_type(8)));
typedef unsigned int uint4v __attribute__((ext_vector_type(4)));

#define MFMA16(A, B, C) __builtin_amdgcn_mfma_f32_16x16x32_bf16(A, B, C, 0, 0, 0)

__device__ __forceinline__ void gload16(const void* g, void* lds) {
  __builtin_amdgcn_global_load_lds((const __attribute__((address_space(1))) void*)g,
                                   (__attribute__((address_space(3))) void*)lds, 16, 0, 0);
}

// ---------- prep: permuted hi/lo bf16 (phl), contiguous f32 (pct), 0.5*|x|^2 ----------
__global__ __launch_bounds__(256)
void prep_kernel(const float* __restrict__ pc, ushort* __restrict__ phl,
                 float* __restrict__ pct, float* __restrict__ sq) {
  __shared__ double psum[256];
  int t = threadIdx.x;
  int u = t >> 5;           // 0..7  (dims u*8 .. u*8+7)
  int p = t & 31;           // 0..31 (point within block)
  int i = blockIdx.x * 32 + p;   // 0..16383
  int b = i >> 13, n = i & (NPTS - 1);
  const float* g = pc + (size_t)b * DIM * NPTS + n;

  float x[8];
  short8 hv, lv;
  double s = 0.0;
  #pragma unroll
  for (int e = 0; e < 8; ++e) {
    x[e] = g[(size_t)(u * 8 + e) * NPTS];
    s += (double)x[e] * (double)x[e];
    unsigned uu = __float_as_uint(x[e]);
    unsigned r = uu + (0x7fffu + ((uu >> 16) & 1));
    unsigned hi = r >> 16;                       // bf16 RNE
    float xl = x[e] - __uint_as_float(hi << 16);
    unsigned ul = __float_as_uint(xl);
    unsigned rl = ul + (0x7fffu + ((ul >> 16) & 1));
    hv[e] = (short)(hi & 0xffffu);
    lv[e] = (short)((rl >> 16) & 0xffffu);
  }
  int slot = u ^ (n & 7);
  ushort* ph = phl + (size_t)i * 128;
  *(short8*)(ph + slot * 8) = hv;
  *(short8*)(ph + 64 + slot * 8) = lv;
  f32x4 v0 = {x[0], x[1], x[2], x[3]}, v1 = {x[4], x[5], x[6], x[7]};
  *(f32x4*)(pct + (size_t)i * 64 + u * 8) = v0;
  *(f32x4*)(pct + (size_t)i * 64 + u * 8 + 4) = v1;

  psum[u * 32 + p] = s;
  __syncthreads();
  if (t < 32) {
    double acc = 0.0;
    #pragma unroll
    for (int uu = 0; uu < 8; ++uu) acc += psum[uu * 32 + t];
    sq[blockIdx.x * 32 + t] = (float)(0.5 * acc);   // HALF |x|^2
  }
}

// ---------- two-pass MFMA distance + theta-filter: barrier-free async LDS pipeline ----------
// 1024 blocks x 256 threads; XCD-partitioned mapping (orig&7 -> (b,seg,row-parity)).
// Block = 32 rows x 4096 cols (64 tiles of 64 cols). Wave w owns cols w*16..+15 of each
// tile AND stages exactly that quarter -> no cross-wave LDS dependency -> no barriers.
// Pipeline: stage(t+1) issued, s_waitcnt vmcnt(5) waits only stage(t); DMA depth 1 tile.
__global__ __launch_bounds__(256, 4)
void knn_kernel(const ushort* __restrict__ phl, const float* __restrict__ sq,
                ushort* __restrict__ cand) {
  __shared__ ushort Bt[2][64 * 128];   // 32 KB double buffer (aliased KT/KT2 in theta phase)
  __shared__ float TH[32];
  __shared__ int CNT[32];
  __shared__ ushort QU[32][QCAP];

  int t = threadIdx.x;
  int lane = t & 63;
  int w = t >> 6;
  int orig = blockIdx.x;
  int x8 = orig & 7;
  int b = x8 >> 2;
  int seg = (x8 >> 1) & 1;
  int row0 = ((orig >> 3) * 2 + (x8 & 1)) * 32;
  const ushort* pb = phl + (size_t)b * NPTS * 128;
  const float* sqb = sq + b * NPTS;

  int c15 = lane & 15, l4 = lane >> 4;
  int sw8 = c15 & 7;
  int so0 = (l4 ^ sw8) * 8;          // kk=0 slot offset (ushorts)
  int so1 = ((4 + l4) ^ sw8) * 8;    // kk=1
  int colbase = seg * 4096;
  int lp = w * 16 + c15;             // tile-local col owned by this lane

  // A fragments [hl][kk][rg], rows row0 + rg*16 + c15, sign-flipped (exact)
  short8 a[2][2][2];
  #pragma unroll
  for (int rg = 0; rg < 2; ++rg) {
    int n = row0 + rg * 16 + c15;
    const ushort* pr = pb + (size_t)n * 128;
    #pragma unroll
    for (int hl = 0; hl < 2; ++hl)
      #pragma unroll
      for (int kk = 0; kk < 2; ++kk) {
        int slot = (kk * 4 + l4) ^ (n & 7);
        short8 v = *(const short8*)(pr + hl * 64 + slot * 8);
        uint4v uv = *(uint4v*)&v;
        uv ^= 0x80008000u;
        a[hl][kk][rg] = *(short8*)&uv;
      }
  }

  // wave w stages its own 16 points (4 KB) of the tile: 4 x gload16, 1 KB each
#define STAGE(BUF, TILE) do { \
    const ushort* src_ = pb + (size_t)(colbase + (TILE) * 64 + w * 16 + (lane >> 4)) * 128 + (lane & 15) * 8; \
    ushort* dst_ = &Bt[BUF][w * 16 * 128]; \
    gload16(src_,        dst_); \
    gload16(src_ + 512,  dst_ + 512); \
    gload16(src_ + 1024, dst_ + 1024); \
    gload16(src_ + 1536, dst_ + 1536); \
  } while (0)

#define COMPKEYS(BUF, SQV, C0, C1) \
    const ushort* bt_ = &Bt[BUF][lp * 128]; \
    short8 bh0 = *(const short8*)(bt_ + so0); \
    short8 bl0 = *(const short8*)(bt_ + 64 + so0); \
    short8 bh1 = *(const short8*)(bt_ + so1); \
    short8 bl1 = *(const short8*)(bt_ + 64 + so1); \
    f32x4 C0 = {SQV, SQV, SQV, SQV}, C1 = C0; \
    C0 = MFMA16(a[0][0][0], bh0, C0); C1 = MFMA16(a[0][0][1], bh0, C1); \
    C0 = MFMA16(a[0][0][0], bl0, C0); C1 = MFMA16(a[0][0][1], bl0, C1); \
    C0 = MFMA16(a[1][0][0], bh0, C0); C1 = MFMA16(a[1][0][1], bh0, C1); \
    C0 = MFMA16(a[0][1][0], bh1, C0); C1 = MFMA16(a[0][1][1], bh1, C1); \
    C0 = MFMA16(a[0][1][0], bl1, C0); C1 = MFMA16(a[0][1][1], bl1, C1); \
    C0 = MFMA16(a[1][1][0], bh1, C0); C1 = MFMA16(a[1][1][1], bh1, C1);

  // ================= PASS A: per-lane top-2 per owned row =================
  float k1[2][4], k2[2][4];
  #pragma unroll
  for (int rg = 0; rg < 2; ++rg)
    #pragma unroll
    for (int r = 0; r < 4; ++r) { k1[rg][r] = __builtin_inff(); k2[rg][r] = __builtin_inff(); }

  asm volatile("s_waitcnt vmcnt(0)" ::: "memory");
  STAGE(0, 0);
  float sqCur = sqb[colbase + lp];
  float sqNxt;
  for (int tt = 0; tt < 63; ++tt) {
    int cur = tt & 1;
    STAGE(cur ^ 1, tt + 1);
    sqNxt = sqb[colbase + (tt + 1) * 64 + lp];
    asm volatile("s_waitcnt vmcnt(5)" ::: "memory");
    COMPKEYS(cur, sqCur, c0, c1);
    #pragma unroll
    for (int r = 0; r < 4; ++r) {
      k2[0][r] = __builtin_amdgcn_fmed3f(c0[r], k1[0][r], k2[0][r]);
      k1[0][r] = fminf(c0[r], k1[0][r]);
      k2[1][r] = __builtin_amdgcn_fmed3f(c1[r], k1[1][r], k2[1][r]);
      k1[1][r] = fminf(c1[r], k1[1][r]);
    }
    sqCur = sqNxt;
  }
  {
    asm volatile("s_waitcnt vmcnt(0)" ::: "memory");
    COMPKEYS(1, sqCur, c0, c1);
    #pragma unroll
    for (int r = 0; r < 4; ++r) {
      k2[0][r] = __builtin_amdgcn_fmed3f(c0[r], k1[0][r], k2[0][r]);
      k1[0][r] = fminf(c0[r], k1[0][r]);
      k2[1][r] = __builtin_amdgcn_fmed3f(c1[r], k1[1][r], k2[1][r]);
      k1[1][r] = fminf(c1[r], k1[1][r]);
    }
  }

  // ================= subset: KT[32][128] -> pair-merge KT2[32][64] (alias dbuf) =================
  __syncthreads();
  float* KT = (float*)&Bt[0][0];    // 16 KB
  float* KT2 = (float*)&Bt[1][0];   // 8 KB
  #pragma unroll
  for (int rg = 0; rg < 2; ++rg)
    #pragma unroll
    for (int r = 0; r < 4; ++r) {
      int row = rg * 16 + l4 * 4 + r;
      KT[row * 128 + (w * 16 + c15) * 2] = k1[rg][r];
      KT[row * 128 + (w * 16 + c15) * 2 + 1] = k2[rg][r];
    }
  __syncthreads();
  #pragma unroll
  for (int it = 0; it < 4; ++it) {
    int idx = t + it * 256;               // 0..1023
    int row = idx >> 5, j = idx & 31;
    float a1 = KT[row * 128 + j * 2], a2 = KT[row * 128 + j * 2 + 1];
    float b1 = KT[row * 128 + 64 + j * 2], b2 = KT[row * 128 + 64 + j * 2 + 1];
    KT2[row * 64 + j * 2] = fminf(a1, b1);
    KT2[row * 64 + j * 2 + 1] = fminf(fmaxf(a1, b1), fminf(a2, b2));
  }
  __syncthreads();

  // ================= theta per row = 22nd smallest of 64-subset =================
  {
    int row = t >> 3;
    int j0 = (t & 7) * 8;
    const f32x4* vr4 = (const f32x4*)(KT2 + row * 64);
    float vj[8];
    *(f32x4*)vj = vr4[(t & 7) * 2];
    *(f32x4*)(vj + 4) = vr4[(t & 7) * 2 + 1];
    int rank[8];
    #pragma unroll
    for (int jj = 0; jj < 8; ++jj) rank[jj] = 0;
    for (int m4 = 0; m4 < 16; ++m4) {
      f32x4 vm = vr4[m4];
      #pragma unroll
      for (int e = 0; e < 4; ++e) {
        int m = m4 * 4 + e;
        float ve = vm[e];
        #pragma unroll
        for (int jj = 0; jj < 8; ++jj)
          rank[jj] += (ve < vj[jj] || (ve == vj[jj] && m < j0 + jj)) ? 1 : 0;
      }
    }
    #pragma unroll
    for (int jj = 0; jj < 8; ++jj)
      if (rank[jj] == THRANK) TH[row] = vj[jj];
    if (t < 32) CNT[t] = 0;
  }
  __syncthreads();
  float th0[4], th1[4];
  #pragma unroll
  for (int r = 0; r < 4; ++r) { th0[r] = TH[l4 * 4 + r]; th1[r] = TH[16 + l4 * 4 + r]; }

  // ================= PASS B: recompute + collect key<=theta =================
  asm volatile("s_waitcnt vmcnt(0)" ::: "memory");
  STAGE(0, 0);
  sqCur = sqb[colbase + lp];
  for (int tt = 0; tt < 63; ++tt) {
    int cur = tt & 1;
    STAGE(cur ^ 1, tt + 1);
    sqNxt = sqb[colbase + (tt + 1) * 64 + lp];
    asm volatile("s_waitcnt vmcnt(5)" ::: "memory");
    COMPKEYS(cur, sqCur, c0, c1);
    int gcol = colbase + tt * 64 + lp;
    #pragma unroll
    for (int r = 0; r < 4; ++r) {
      if (c0[r] <= th0[r]) {
        int rw = l4 * 4 + r;
        int pos = atomicAdd(&CNT[rw], 1);
        if (pos < QCAP) QU[rw][pos] = (ushort)gcol;
      }
      if (c1[r] <= th1[r]) {
        int rw = 16 + l4 * 4 + r;
        int pos = atomicAdd(&CNT[rw], 1);
        if (pos < QCAP) QU[rw][pos] = (ushort)gcol;
      }
    }
    sqCur = sqNxt;
  }
  {
    asm volatile("s_waitcnt vmcnt(0)" ::: "memory");
    COMPKEYS(1, sqCur, c0, c1);
    int gcol = colbase + 63 * 64 + lp;
    #pragma unroll
    for (int r = 0; r < 4; ++r) {
      if (c0[r] <= th0[r]) {
        int rw = l4 * 4 + r;
        int pos = atomicAdd(&CNT[rw], 1);
        if (pos < QCAP) QU[rw][pos] = (ushort)gcol;
      }
      if (c1[r] <= th1[r]) {
        int rw = 16 + l4 * 4 + r;
        int pos = atomicAdd(&CNT[rw], 1);
        if (pos < QCAP) QU[rw][pos] = (ushort)gcol;
      }
    }
  }

  // ================= pad + dump queues =================
  __syncthreads();
  for (int i = t; i < 32 * QCAP; i += 256) {
    int row = i / QCAP, s2 = i % QCAP;
    int c2 = CNT[row]; if (c2 > QCAP) c2 = QCAP;
    ushort v = (s2 < c2) ? QU[row][s2] : (ushort)0xFFFFu;
    cand[((size_t)(b * NPTS + row0 + row) * 2 + seg) * QCAP + s2] = v;
  }
}

// ---------- exact f64 re-rank of up to 80 candidates, wave per point ----------
__global__ void refine_kernel(const float* __restrict__ pct, const ushort* __restrict__ cand,
                              int* __restrict__ knn, float* __restrict__ idxf) {
  int gw = (blockIdx.x * 256 + threadIdx.x) >> 6;  // 0..16383
  int lane = threadIdx.x & 63;
  int b = gw >> 13, n = gw & (NPTS - 1);
  const float* pcb = pct + (size_t)b * NPTS * 64;
  const ushort* cb = cand + (size_t)gw * (2 * QCAP);
  const float* qp = pcb + (size_t)n * 64;

  unsigned ciA = cb[lane];
  unsigned ciB = (lane < 2 * QCAP - 64) ? (unsigned)cb[64 + lane] : 0xFFFFu;
  double dA = __builtin_inf(), dB = __builtin_inf();
  if (ciA != 0xFFFFu) {
    const float* cp = pcb + (size_t)ciA * 64;
    double s = 0.0;
    #pragma unroll
    for (int u = 0; u < 16; ++u) {
      f32x4 cv = *(const f32x4*)(cp + u * 4);
      f32x4 qv = *(const f32x4*)(qp + u * 4);
      #pragma unroll
      for (int e = 0; e < 4; ++e) {
        double diff = (double)cv[e] - (double)qv[e];
        s = fma(diff, diff, s);
      }
    }
    dA = s;
  }
  if (ciB != 0xFFFFu) {
    const float* cp = pcb + (size_t)ciB * 64;
    double s = 0.0;
    #pragma unroll
    for (int u = 0; u < 16; ++u) {
      f32x4 cv = *(const f32x4*)(cp + u * 4);
      f32x4 qv = *(const f32x4*)(qp + u * 4);
      #pragma unroll
      for (int e = 0; e < 4; ++e) {
        double diff = (double)cv[e] - (double)qv[e];
        s = fma(diff, diff, s);
      }
    }
    dB = s;
  }

  int rA = 0, rB = 0;
  for (int j = 0; j < 64; ++j) {
    double dk = __shfl(dA, j);
    unsigned ik = (unsigned)__shfl((int)ciA, j);
    rA += ((dk < dA) || (dk == dA && ik < ciA)) ? 1 : 0;
    rB += ((dk < dB) || (dk == dB && ik < ciB)) ? 1 : 0;
  }
  for (int j = 0; j < 2 * QCAP - 64; ++j) {
    double dk = __shfl(dB, j);
    unsigned ik = (unsigned)__shfl((int)ciB, j);
    rA += ((dk < dA) || (dk == dA && ik < ciA)) ? 1 : 0;
    rB += ((dk < dB) || (dk == dB && ik < ciB)) ? 1 : 0;
  }
  if (ciA != 0xFFFFu && rA < KOUT) {
    size_t o = ((size_t)b * KOUT + rA) * NPTS + n;
    knn[o] = (int)ciA;
    idxf[o] = (float)ciA;
  }
  if (lane < 2 * QCAP - 64 && ciB != 0xFFFFu && rB < KOUT) {
    size_t o = ((size_t)b * KOUT + rB) * NPTS + n;
    knn[o] = (int)ciB;
    idxf[o] = (float)ciB;
  }
}

// ---------- edge features: out [B][128][17][N]; thread handles 4 n-values (float4) ----------
__global__ __launch_bounds__(256)
void edge_kernel(const float* __restrict__ pc, const int* __restrict__ knn,
                 float* __restrict__ out) {
  int n = (blockIdx.x * 256 + threadIdx.x) * 4;
  int z = blockIdx.y;
  int b = z >> 6, c = z & 63;
  const float* row = pc + ((size_t)b * DIM + c) * NPTS;
  f32x4 central = *(const f32x4*)(row + n);
  size_t base = (((size_t)b * 2 * DIM + c) * KOUT) * NPTS + n;
  const int* kb = knn + (size_t)b * KOUT * NPTS + n;
  #pragma unroll
  for (int k = 0; k < KOUT; ++k) {
    int4 nb = *(const int4*)(kb + (size_t)k * NPTS);
    f32x4 nv = {row[nb.x], row[nb.y], row[nb.z], row[nb.w]};
    *(f32x4*)(out + base + (size_t)k * NPTS) = central;
    *(f32x4*)(out + base + (size_t)(DIM * KOUT + k) * NPTS) = nv - central;
  }
}

extern "C" void kernel_launch(void* const* d_in, const int* in_sizes, int n_in,
                              void* d_out, int out_size, void* d_ws, size_t ws_size,
                              hipStream_t stream) {
  const float* pc = (const float*)d_in[0];
  float* out = (float*)d_out;
  char* ws = (char*)d_ws;
  ushort* phl = (ushort*)ws;                                     // 4 MB
  float* pct  = (float*)(ws + (size_t)4 * 1024 * 1024);          // 4 MB
  float* sq   = (float*)(ws + (size_t)8 * 1024 * 1024);          // 64 KB
  ushort* cand = (ushort*)(ws + (size_t)8 * 1024 * 1024 + 65536);
  int* knn    = (int*)(ws + (size_t)8 * 1024 * 1024 + 65536 + (size_t)16384 * 2 * QCAP * 2);

  float* idxf = out + (size_t)BATCH * 2 * DIM * KOUT * NPTS;

  prep_kernel<<<512, 256, 0, stream>>>(pc, phl, pct, sq);
  knn_kernel<<<1024, 256, 0, stream>>>(phl, sq, cand);
  refine_kernel<<<4096, 256, 0, stream>>>(pct, cand, knn, idxf);
  edge_kernel<<<dim3(NPTS / 1024, BATCH * DIM), 256, 0, stream>>>(pc, knn, out);
}